// Round 5
// baseline (399.667 us; speedup 1.0000x reference)
//
#include <hip/hip_runtime.h>
#include <cstdint>

#define DEVINL __device__ __forceinline__

typedef uint16_t u16;
typedef uint32_t u32;
typedef uint64_t u64;
typedef __attribute__((ext_vector_type(8))) short short8;
typedef __attribute__((ext_vector_type(4))) float floatx4;
typedef __attribute__((ext_vector_type(4))) u32 u32x4;
typedef __attribute__((ext_vector_type(2))) u32 u32x2;
typedef const __attribute__((address_space(1))) void* gas_ptr;
typedef __attribute__((address_space(3))) void* las_ptr;

DEVINL u16 f2bf(float f) {
  u32 u = __float_as_uint(f);
  u32 r = u + 0x7FFFu + ((u >> 16) & 1u);   // RNE
  return (u16)(r >> 16);
}
DEVINL float bf2f(u16 b) { return __uint_as_float((u32)b << 16); }
DEVINL float bf_lo(u32 u) { return __uint_as_float(u << 16); }
DEVINL float bf_hi(u32 u) { return __uint_as_float(u & 0xFFFF0000u); }

// Operand layout for GEMM: K-chunked tiles  T[ck][row][64], ck = k/64.
// A' rows padded to Mpad=25088 so block row-tiles read contiguous 16KB with no clamp
// (garbage rows feed MFMA but their outputs are store-guarded).

// ---------- row_start[n] = lower_bound(dst, n) over sorted dst ----------
__global__ void rowstart_kernel(const int* __restrict__ dst, int* __restrict__ rs,
                                int N, int E) {
  int n = blockIdx.x * blockDim.x + threadIdx.x;
  if (n > N) return;
  int lo = 0, hi = E;
  while (lo < hi) { int mid = (lo + hi) >> 1; if (dst[mid] < n) lo = mid + 1; else hi = mid; }
  rs[n] = lo;
}

// zero z3 + el + er in one launch (layer-3 atomic targets)
__global__ void zero3_kernel(float* __restrict__ z3, float* __restrict__ el,
                             float* __restrict__ er, int nz, int ne) {
  int i = blockIdx.x * blockDim.x + threadIdx.x;
  if (i < nz) { z3[i] = 0.f; return; }
  int j = i - nz;
  if (j < ne) { el[j] = 0.f; return; }
  j -= ne;
  if (j < ne) er[j] = 0.f;
}

// ---------- h (f32 [N][256]) -> A1 tiled [8][Mpad][64], exact hi/lo split ----------
__global__ __launch_bounds__(256)
void splitA_kernel(const float* __restrict__ in, u16* __restrict__ out,
                   int M, int Mpad) {
  int idx = blockIdx.x * blockDim.x + threadIdx.x;
  if (idx >= M * 256) return;
  int m = idx >> 8, k = idx & 255;
  float a = in[idx];
  u16 h = f2bf(a);
  u16 lo = f2bf(a - bf2f(h));
  size_t cs = (size_t)Mpad * 64;
  size_t pos = (size_t)m * 64 + (k & 63);
  out[(size_t)(k >> 6) * cs + pos] = h;          // hi chunks 0..3
  out[(size_t)((k >> 6) + 4) * cs + pos] = lo;   // lo chunks 4..7
}

// ---------- W1/W2/W3 -> B1/B2/B3 tiled (bf16 hi duplicated), one launch ----------
__global__ __launch_bounds__(256)
void splitW_kernel(const float* __restrict__ W1, const float* __restrict__ W2,
                   const float* __restrict__ W3, u16* __restrict__ B1,
                   u16* __restrict__ B2, u16* __restrict__ B3) {
  int idx = blockIdx.x * blockDim.x + threadIdx.x;
  if (idx < 512 * 256) {                          // W1 [512][256] -> [8][512][64]
    int m = idx >> 8, k = idx & 255;
    u16 h = f2bf(W1[idx]);
    size_t cs = 512 * 64;
    size_t pos = (size_t)m * 64 + (k & 63);
    B1[(size_t)(k >> 6) * cs + pos] = h;
    B1[(size_t)((k >> 6) + 4) * cs + pos] = h;
    return;
  }
  idx -= 512 * 256;
  if (idx < 512 * 512) {                          // W2 [512][512] -> [16][512][64]
    int m = idx >> 9, k = idx & 511;
    u16 h = f2bf(W2[idx]);
    size_t cs = 512 * 64;
    size_t pos = (size_t)m * 64 + (k & 63);
    B2[(size_t)(k >> 6) * cs + pos] = h;
    B2[(size_t)((k >> 6) + 8) * cs + pos] = h;
    return;
  }
  idx -= 512 * 512;
  if (idx < 32 * 512) {                           // W3 [32][512] -> [16][32][64]
    int m = idx >> 9, k = idx & 511;
    u16 h = f2bf(W3[idx]);
    size_t cs = 32 * 64;
    size_t pos = (size_t)m * 64 + (k & 63);
    B3[(size_t)(k >> 6) * cs + pos] = h;
    B3[(size_t)((k >> 6) + 8) * cs + pos] = h;
  }
}

// ---------- GEMM: C[M,Nout] = A'[M,K'] * B'[Nout,K']^T, K-chunked operands ----------
// BM=128, BK=64 (one chunk/step), 256 threads (4 waves); wave w owns rows [32w,32w+32).
// Staging: one global_load_lds call = 64 lanes x 16B = 512 u16 = 8 tile-rows.
//   A tile = 128x64 u16 = 16 calls (4/wave). B tile = BNx64 = BN/8 calls.
// LDS XOR-swizzle (granule ^= row&7): pre-swizzled GLOBAL source + swizzled ds_read,
// linear global_load_lds dest (rule: both-sides-or-neither). Conflict-free b128 reads.
// OUTM 1: bf16 C store + el/er store epilogue; XCD-grouped bid decode (the 4 column
//         blocks of one row-tile land on one XCD -> A-tile fetched once per L2).
// OUTM 2: split-K f32 atomicAdd + el/er atomicAdd epilogue.
template<int BN, int OUTM>
__global__ __launch_bounds__(256)
void gemm_bt_kernel(const u16* __restrict__ A, const u16* __restrict__ B,
                    float* __restrict__ Cf, u16* __restrict__ Cb,
                    const float* __restrict__ al, const float* __restrict__ ar,
                    float* __restrict__ el, float* __restrict__ er,
                    int M, int Nout, int Mpad, int kcLen)
{
  constexpr int BM = 128, CF = BN / 16;
  constexpr int BCALLS_B = (BN * 64) / 512;       // 16 for BN=128, 4 for BN=32
  __shared__ __align__(16) u16 As[BM * 64];       // 16 KB
  __shared__ __align__(16) u16 Bs[BN * 64];
  const int tid  = threadIdx.x;
  const int wave = tid >> 6;
  const int lane = tid & 63;
  const int quad = lane >> 4;
  const int l16  = lane & 15;
  const int lrow = lane >> 3;                     // sub-row within a 512-elem call
  const int lq   = lane & 7;                      // 16B-granule within row

  int bx, by;
  if (OUTM == 1) {
    // XCD grouping: bid = y%8 + 8*x + 32*(y/8) for full groups of 8 y's.
    int bid = blockIdx.x;
    int nY = (M + 127) >> 7;
    int fullG = nY >> 3;
    if ((bid >> 5) < fullG) {
      int rem = bid & 31;
      by = ((bid >> 5) << 3) + (rem & 7);
      bx = rem >> 3;
    } else {
      int t = bid - (fullG << 5);
      int tailY = nY - (fullG << 3);
      by = (fullG << 3) + t % tailY;
      bx = t / tailY;
    }
  } else { bx = blockIdx.x; by = blockIdx.y; }

  const int rowBase = by * BM;
  const int colBase = (OUTM == 2) ? 0 : bx * BN;
  const int kcStart = (OUTM == 2) ? bx * kcLen : 0;

  floatx4 acc[2][CF];
  #pragma unroll
  for (int r = 0; r < 2; ++r)
    #pragma unroll
    for (int c = 0; c < CF; ++c)
      acc[r][c] = (floatx4){0.f, 0.f, 0.f, 0.f};

  const size_t aCS = (size_t)Mpad * 64;
  const size_t bCS = (size_t)Nout * 64;
  const u16* aTile = A + (size_t)rowBase * 64;
  const u16* bTile = B + (size_t)colBase * 64;

  for (int kc = kcStart; kc < kcStart + kcLen; ++kc) {
    __syncthreads();
    const u16* aB = aTile + (size_t)kc * aCS;
    #pragma unroll
    for (int i = 0; i < 4; ++i) {                 // A: 16 calls, 4/wave (16KB tile)
      int c = wave * 4 + i;
      int row = c * 8 + lrow;
      const u16* gp = aB + row * 64 + (((lq ^ (row & 7))) << 3);
      __builtin_amdgcn_global_load_lds((gas_ptr)gp, (las_ptr)(As + c * 512), 16, 0, 0);
    }
    const u16* bB = bTile + (size_t)kc * bCS;
    #pragma unroll
    for (int i = 0; i < BCALLS_B / 4; ++i) {      // B: BCALLS_B calls
      int c = wave * (BCALLS_B / 4) + i;
      int row = c * 8 + lrow;
      const u16* gp = bB + row * 64 + (((lq ^ (row & 7))) << 3);
      __builtin_amdgcn_global_load_lds((gas_ptr)gp, (las_ptr)(Bs + c * 512), 16, 0, 0);
    }
    __syncthreads();
    #pragma unroll
    for (int kk = 0; kk < 2; ++kk) {              // 32 MFMA per barrier drain
      const int r0 = 32 * wave + l16;
      const int r1 = r0 + 16;
      short8 a0 = *(const short8*)(As + r0 * 64 + ((((kk << 2) + quad) ^ (r0 & 7)) << 3));
      short8 a1 = *(const short8*)(As + r1 * 64 + ((((kk << 2) + quad) ^ (r1 & 7)) << 3));
      #pragma unroll
      for (int c = 0; c < CF; ++c) {
        int rb = 16 * c + l16;
        short8 b = *(const short8*)(Bs + rb * 64 + ((((kk << 2) + quad) ^ (rb & 7)) << 3));
        acc[0][c] = __builtin_amdgcn_mfma_f32_16x16x32_bf16(a0, b, acc[0][c], 0, 0, 0);
        acc[1][c] = __builtin_amdgcn_mfma_f32_16x16x32_bf16(a1, b, acc[1][c], 0, 0, 0);
      }
    }
  }

  // C/D layout: col = lane&15, row = quad*4 + reg (verified m89/m91)
  #pragma unroll
  for (int rt = 0; rt < 2; ++rt)
    #pragma unroll
    for (int c = 0; c < CF; ++c)
      #pragma unroll
      for (int i = 0; i < 4; ++i) {
        int gr = rowBase + 32 * wave + 16 * rt + quad * 4 + i;
        if (gr < M) {
          int gc = colBase + 16 * c + l16;
          if (OUTM == 1) Cb[(size_t)gr * Nout + gc] = f2bf(acc[rt][c][i]);
          else           atomicAdd(Cf + (size_t)gr * Nout + gc, acc[rt][c][i]);
        }
      }

  // ---- fused el/er epilogue (from f32 acc) ----
  if (OUTM == 1) {
    #pragma unroll
    for (int rt = 0; rt < 2; ++rt)
      #pragma unroll
      for (int i = 0; i < 4; ++i) {
        int gr = rowBase + 32 * wave + 16 * rt + quad * 4 + i;
        #pragma unroll
        for (int hp = 0; hp < 2; ++hp) {
          float sl = 0.f, sr = 0.f;
          #pragma unroll
          for (int cc = 0; cc < 4; ++cc) {
            int c = hp * 4 + cc;
            int gc = colBase + 16 * c + l16;
            float zv = acc[rt][c][i];
            sl += zv * al[gc];
            sr += zv * ar[gc];
          }
          #pragma unroll
          for (int m = 1; m < 16; m <<= 1) {
            sl += __shfl_xor(sl, m, 64);
            sr += __shfl_xor(sr, m, 64);
          }
          if (l16 == 0 && gr < M) {
            int hh = colBase / 64 + hp;
            el[(size_t)gr * 8 + hh] = sl;
            er[(size_t)gr * 8 + hh] = sr;
          }
        }
      }
  } else {
    #pragma unroll
    for (int rt = 0; rt < 2; ++rt)
      #pragma unroll
      for (int i = 0; i < 4; ++i) {
        int gr = rowBase + 32 * wave + 16 * rt + quad * 4 + i;
        float sl = 0.f, sr = 0.f;
        #pragma unroll
        for (int c = 0; c < CF; ++c) {
          int gc = 16 * c + l16;
          float zv = acc[rt][c][i];
          sl += zv * al[gc];
          sr += zv * ar[gc];
        }
        #pragma unroll
        for (int m = 1; m < 16; m <<= 1) {
          sl += __shfl_xor(sl, m, 64);
          sr += __shfl_xor(sr, m, 64);
        }
        if (l16 == 0 && gr < M) {
          atomicAdd(el + gr, sl);
          atomicAdd(er + gr, sr);
        }
      }
  }
}

// ---------- layers 1/2 aggregate: bf16 z gather, COLUMN-HALF passes ----------
// out = sum_e exp(v_e) z[src_e] / sum_e exp(v_e)  (shift-invariant softmax, no max pass)
// R5: two sequential dispatches per layer (cbase = 0, 256). Each pass touches only
// 512B/row -> 12.8MB distinct-line working set (vs 25.6MB), raising the L2 hit rate
// on the ~3.7 TB/s miss-path that r0/r1 showed is the binding ceiling. Per-pass math
// (den order, acc order) identical to the full-width version -> bit-identical output.
// 4 cols/lane (8B). Epilogue writes this pass's A' chunks: hi ck=c0/64, lo ck+8.
__global__ __launch_bounds__(64)
void agg_bf16_kernel(const u16* __restrict__ z, const float* __restrict__ el,
                     const float* __restrict__ er, const int* __restrict__ src,
                     const int* __restrict__ rs, u16* __restrict__ a2out,
                     int Mpad, int cbase)
{
  const int n = blockIdx.x, tid = threadIdx.x;
  const int s = rs[n], e = rs[n + 1];
  const int c0 = cbase + tid * 4;                  // 4 bf16 cols = 8 B/lane
  const int h = c0 >> 6;
  const float er_h = er[(size_t)n * 8 + h];

  float acc[4];
  #pragma unroll
  for (int j = 0; j < 4; ++j) acc[j] = 0.f;
  float den = 0.f;

  for (int k0 = s; k0 < e; k0 += 8) {
    const int kc = e - k0;
    #pragma unroll
    for (int kk = 0; kk < 8; ++kk) {
      if (kk < kc) {                               // wave-uniform guard
        int si = src[k0 + kk];                     // broadcast load
        float v = el[(size_t)si * 8 + h] + er_h;   // broadcast load
        v = (v > 0.f) ? v : 0.2f * v;              // leaky_relu 0.2
        float wgt = __expf(v);
        u32x2 zz = *(const u32x2*)(z + (size_t)si * 512 + c0);  // 8B/lane coalesced
        acc[0] += wgt * bf_lo(zz[0]);
        acc[1] += wgt * bf_hi(zz[0]);
        acc[2] += wgt * bf_lo(zz[1]);
        acc[3] += wgt * bf_hi(zz[1]);
        den += wgt;
      }
    }
  }

  const float r = (e > s) ? (1.f / den) : 0.f;     // deg==0 -> zeros (elu(0)=0)
  u32x2 hp, lp;
  #pragma unroll
  for (int j = 0; j < 2; ++j) {
    float o0 = acc[2 * j] * r, o1 = acc[2 * j + 1] * r;
    o0 = (o0 > 0.f) ? o0 : (__expf(o0) - 1.f);     // elu
    o1 = (o1 > 0.f) ? o1 : (__expf(o1) - 1.f);
    u16 h0 = f2bf(o0), h1 = f2bf(o1);
    u16 l0 = f2bf(o0 - bf2f(h0)), l1 = f2bf(o1 - bf2f(h1));
    hp[j] = ((u32)h1 << 16) | h0;
    lp[j] = ((u32)l1 << 16) | l0;
  }
  // tiled A' store: chunk = c0/64, offset = c0%64 (16 lanes -> 128B contiguous runs)
  const int ck = c0 >> 6;
  const int ko = c0 & 63;
  const size_t cs = (size_t)Mpad * 64;
  u16* p = a2out + (size_t)n * 64 + ko;
  *(u32x2*)(p + (size_t)ck * cs) = hp;
  *(u32x2*)(p + (size_t)(ck + 8) * cs) = lp;
}

// ---------- layer 3 aggregate: f32 z3 (3.2 MB, L2-resident), 32 cols ----------
__global__ __launch_bounds__(64)
void agg3_kernel(const float* __restrict__ z, const float* __restrict__ el,
                 const float* __restrict__ er, const int* __restrict__ src,
                 const int* __restrict__ rs, float* __restrict__ out)
{
  const int n = blockIdx.x, tid = threadIdx.x;
  const int s = rs[n], e = rs[n + 1];
  const bool active = (tid < 32);
  const float er_n = er[n];
  float acc = 0.f, den = 0.f;

  for (int k0 = s; k0 < e; k0 += 8) {
    const int kc = e - k0;
    #pragma unroll
    for (int kk = 0; kk < 8; ++kk) {
      if (kk < kc) {
        int si = src[k0 + kk];
        float v = el[si] + er_n;
        v = (v > 0.f) ? v : 0.2f * v;
        float wgt = __expf(v);
        if (active) acc += wgt * z[(size_t)si * 32 + tid];
        den += wgt;
      }
    }
  }
  if (active) out[(size_t)n * 32 + tid] = (e > s) ? (acc / den) : 0.f;
}

extern "C" void kernel_launch(void* const* d_in, const int* in_sizes, int n_in,
                              void* d_out, int out_size, void* d_ws, size_t ws_size,
                              hipStream_t stream)
{
  constexpr int N = 25000, E = 400000, K1 = 256, HF = 512, CLS = 32;
  constexpr int Mpad = 25088;                       // 196 * 128
  const float* h   = (const float*)d_in[0];
  const int*   src = (const int*)d_in[1];
  const int*   dst = (const int*)d_in[2];
  const float* W1  = (const float*)d_in[3];
  const float* al1 = (const float*)d_in[4];
  const float* ar1 = (const float*)d_in[5];
  const float* W2  = (const float*)d_in[6];
  const float* al2 = (const float*)d_in[7];
  const float* ar2 = (const float*)d_in[8];
  const float* W3  = (const float*)d_in[9];
  const float* al3 = (const float*)d_in[10];
  const float* ar3 = (const float*)d_in[11];
  float* out = (float*)d_out;

  char* w = (char*)d_ws;
  auto take = [&](size_t bytes) {
    char* p = w;
    w += (bytes + 255) & ~(size_t)255;
    return p;
  };
  int*   rs = (int*)  take((size_t)(N + 1) * sizeof(int));
  float* el = (float*)take((size_t)N * 8 * sizeof(float));
  float* er = (float*)take((size_t)N * 8 * sizeof(float));
  float* z3 = (float*)take((size_t)N * CLS * sizeof(float));          // 3.2 MB
  u16*   zb = (u16*)  take((size_t)N * HF * sizeof(u16));             // 25.6 MB
  u16*   A2 = (u16*)  take((size_t)16 * Mpad * 64 * sizeof(u16));     // 51.4 MB
  u16*   B1 = (u16*)  take((size_t)8  * HF * 64 * sizeof(u16));       // 0.52 MB
  u16*   B2 = (u16*)  take((size_t)16 * HF * 64 * sizeof(u16));       // 1.05 MB
  u16*   B3 = (u16*)  take((size_t)16 * CLS * 64 * sizeof(u16));      // 64 KB
  u16*   A1 = A2;       // layer-1 A (8 chunks) aliases A2; dead before agg1 writes

  // ---- independent prep ----
  rowstart_kernel<<<dim3((N + 1 + 255) / 256), 256, 0, stream>>>(dst, rs, N, E);
  splitA_kernel<<<dim3((N * K1) / 256), 256, 0, stream>>>(h, A1, N, Mpad);
  splitW_kernel<<<dim3(1600), 256, 0, stream>>>(W1, W2, W3, B1, B2, B3);

  const int gemmBlocks = 4 * (Mpad / 128);          // 784, 1-D XCD-grouped decode

  // ---- Layer 1: K'=512 (8 chunks), elr fused ----
  gemm_bt_kernel<128, 1><<<dim3(gemmBlocks), 256, 0, stream>>>(A1, B1, nullptr, zb,
      al1, ar1, el, er, N, HF, Mpad, 8);
  agg_bf16_kernel<<<dim3(N), 64, 0, stream>>>(zb, el, er, src, rs, A2, Mpad, 0);
  agg_bf16_kernel<<<dim3(N), 64, 0, stream>>>(zb, el, er, src, rs, A2, Mpad, 256);

  // ---- Layer 2: K'=1024 (16 chunks), elr fused ----
  gemm_bt_kernel<128, 1><<<dim3(gemmBlocks), 256, 0, stream>>>(A2, B2, nullptr, zb,
      al2, ar2, el, er, N, HF, Mpad, 16);
  agg_bf16_kernel<<<dim3(N), 64, 0, stream>>>(zb, el, er, src, rs, A2, Mpad, 0);
  agg_bf16_kernel<<<dim3(N), 64, 0, stream>>>(zb, el, er, src, rs, A2, Mpad, 256);

  // ---- Layer 3: split-K=4 (4 chunks each) + atomicAdd, elr fused (atomic) ----
  zero3_kernel<<<dim3((N * CLS + 2 * N + 255) / 256), 256, 0, stream>>>(z3, el, er, N * CLS, N);
  gemm_bt_kernel<32, 2><<<dim3(4, Mpad / 128), 256, 0, stream>>>(A2, B3, z3, nullptr,
      al3, ar3, el, er, N, CLS, Mpad, 4);
  agg3_kernel<<<dim3(N), 64, 0, stream>>>(z3, el, er, src, rs, out);
}

// Round 6
// 374.846 us; speedup vs baseline: 1.0662x; 1.0662x over previous
//
#include <hip/hip_runtime.h>
#include <cstdint>

#define DEVINL __device__ __forceinline__

typedef uint16_t u16;
typedef uint32_t u32;
typedef uint64_t u64;
typedef __attribute__((ext_vector_type(8))) short short8;
typedef __attribute__((ext_vector_type(4))) float floatx4;
typedef __attribute__((ext_vector_type(4))) u32 u32x4;
typedef const __attribute__((address_space(1))) void* gas_ptr;
typedef __attribute__((address_space(3))) void* las_ptr;

DEVINL u16 f2bf(float f) {
  u32 u = __float_as_uint(f);
  u32 r = u + 0x7FFFu + ((u >> 16) & 1u);   // RNE
  return (u16)(r >> 16);
}
DEVINL float bf2f(u16 b) { return __uint_as_float((u32)b << 16); }
DEVINL float bf_lo(u32 u) { return __uint_as_float(u << 16); }
DEVINL float bf_hi(u32 u) { return __uint_as_float(u & 0xFFFF0000u); }

// Operand layout for GEMM: K-chunked tiles  T[ck][row][64], ck = k/64.
// A' rows padded to Mpad=25088 so block row-tiles read contiguous 16KB with no clamp
// (garbage rows feed MFMA but their outputs are store-guarded).

// ---------- row_start[n] = lower_bound(dst, n) over sorted dst ----------
__global__ void rowstart_kernel(const int* __restrict__ dst, int* __restrict__ rs,
                                int N, int E) {
  int n = blockIdx.x * blockDim.x + threadIdx.x;
  if (n > N) return;
  int lo = 0, hi = E;
  while (lo < hi) { int mid = (lo + hi) >> 1; if (dst[mid] < n) lo = mid + 1; else hi = mid; }
  rs[n] = lo;
}

// zero z3 + el + er in one launch (layer-3 atomic targets)
__global__ void zero3_kernel(float* __restrict__ z3, float* __restrict__ el,
                             float* __restrict__ er, int nz, int ne) {
  int i = blockIdx.x * blockDim.x + threadIdx.x;
  if (i < nz) { z3[i] = 0.f; return; }
  int j = i - nz;
  if (j < ne) { el[j] = 0.f; return; }
  j -= ne;
  if (j < ne) er[j] = 0.f;
}

// ---------- h (f32 [N][256]) -> A1 tiled [8][Mpad][64], exact hi/lo split ----------
__global__ __launch_bounds__(256)
void splitA_kernel(const float* __restrict__ in, u16* __restrict__ out,
                   int M, int Mpad) {
  int idx = blockIdx.x * blockDim.x + threadIdx.x;
  if (idx >= M * 256) return;
  int m = idx >> 8, k = idx & 255;
  float a = in[idx];
  u16 h = f2bf(a);
  u16 lo = f2bf(a - bf2f(h));
  size_t cs = (size_t)Mpad * 64;
  size_t pos = (size_t)m * 64 + (k & 63);
  out[(size_t)(k >> 6) * cs + pos] = h;          // hi chunks 0..3
  out[(size_t)((k >> 6) + 4) * cs + pos] = lo;   // lo chunks 4..7
}

// ---------- W1/W2/W3 -> B1/B2/B3 tiled (bf16 hi duplicated), one launch ----------
__global__ __launch_bounds__(256)
void splitW_kernel(const float* __restrict__ W1, const float* __restrict__ W2,
                   const float* __restrict__ W3, u16* __restrict__ B1,
                   u16* __restrict__ B2, u16* __restrict__ B3) {
  int idx = blockIdx.x * blockDim.x + threadIdx.x;
  if (idx < 512 * 256) {                          // W1 [512][256] -> [8][512][64]
    int m = idx >> 8, k = idx & 255;
    u16 h = f2bf(W1[idx]);
    size_t cs = 512 * 64;
    size_t pos = (size_t)m * 64 + (k & 63);
    B1[(size_t)(k >> 6) * cs + pos] = h;
    B1[(size_t)((k >> 6) + 4) * cs + pos] = h;
    return;
  }
  idx -= 512 * 256;
  if (idx < 512 * 512) {                          // W2 [512][512] -> [16][512][64]
    int m = idx >> 9, k = idx & 511;
    u16 h = f2bf(W2[idx]);
    size_t cs = 512 * 64;
    size_t pos = (size_t)m * 64 + (k & 63);
    B2[(size_t)(k >> 6) * cs + pos] = h;
    B2[(size_t)((k >> 6) + 8) * cs + pos] = h;
    return;
  }
  idx -= 512 * 512;
  if (idx < 32 * 512) {                           // W3 [32][512] -> [16][32][64]
    int m = idx >> 9, k = idx & 511;
    u16 h = f2bf(W3[idx]);
    size_t cs = 32 * 64;
    size_t pos = (size_t)m * 64 + (k & 63);
    B3[(size_t)(k >> 6) * cs + pos] = h;
    B3[(size_t)((k >> 6) + 8) * cs + pos] = h;
  }
}

// ---------- GEMM: C[M,Nout] = A'[M,K'] * B'[Nout,K']^T, K-chunked operands ----------
// BM=128, BK=64 (one chunk/step), 256 threads (4 waves); wave w owns rows [32w,32w+32).
// R6: 2-PHASE double-buffered pipeline (T3/T4 minimum recipe): STAGE(t+1) is issued
// BEFORE the compute on tile t, one barrier per K-step. The barrier's implicit
// vmcnt(0) drain then lands after the MFMA phase has covered the load latency
// (the R5 structure drained with zero compute in flight -> MfmaUtil 17%).
// Barrier correctness: at iter t's __syncthreads, every wave's iter t-1 ds_reads
// have completed (lgkmcnt waits precede the consuming MFMAs, which precede the
// barrier in program order), so STAGE writes into buf[cur^1] after it are safe.
// Staging: one global_load_lds call = 64 lanes x 16B = 512 u16 = 8 tile-rows.
// LDS XOR-swizzle (granule ^= row&7): pre-swizzled GLOBAL source + swizzled ds_read.
// OUTM 1: bf16 C store + el/er store epilogue; XCD-grouped bid decode.
// OUTM 2: split-K f32 atomicAdd + el/er atomicAdd epilogue.
template<int BN, int OUTM>
__global__ __launch_bounds__(256)
void gemm_bt_kernel(const u16* __restrict__ A, const u16* __restrict__ B,
                    float* __restrict__ Cf, u16* __restrict__ Cb,
                    const float* __restrict__ al, const float* __restrict__ ar,
                    float* __restrict__ el, float* __restrict__ er,
                    int M, int Nout, int Mpad, int kcLen)
{
  constexpr int BM = 128, CF = BN / 16;
  constexpr int BCALLS_B = (BN * 64) / 512;       // 16 for BN=128, 4 for BN=32
  __shared__ __align__(16) u16 As[2][BM * 64];    // 2 x 16 KB
  __shared__ __align__(16) u16 Bs[2][BN * 64];
  const int tid  = threadIdx.x;
  const int wave = tid >> 6;
  const int lane = tid & 63;
  const int quad = lane >> 4;
  const int l16  = lane & 15;
  const int lrow = lane >> 3;                     // sub-row within a 512-elem call
  const int lq   = lane & 7;                      // 16B-granule within row

  int bx, by;
  if (OUTM == 1) {
    // XCD grouping: bid = y%8 + 8*x + 32*(y/8) for full groups of 8 y's.
    int bid = blockIdx.x;
    int nY = (M + 127) >> 7;
    int fullG = nY >> 3;
    if ((bid >> 5) < fullG) {
      int rem = bid & 31;
      by = ((bid >> 5) << 3) + (rem & 7);
      bx = rem >> 3;
    } else {
      int t = bid - (fullG << 5);
      int tailY = nY - (fullG << 3);
      by = (fullG << 3) + t % tailY;
      bx = t / tailY;
    }
  } else { bx = blockIdx.x; by = blockIdx.y; }

  const int rowBase = by * BM;
  const int colBase = (OUTM == 2) ? 0 : bx * BN;
  const int kcStart = (OUTM == 2) ? bx * kcLen : 0;

  floatx4 acc[2][CF];
  #pragma unroll
  for (int r = 0; r < 2; ++r)
    #pragma unroll
    for (int c = 0; c < CF; ++c)
      acc[r][c] = (floatx4){0.f, 0.f, 0.f, 0.f};

  const size_t aCS = (size_t)Mpad * 64;
  const size_t bCS = (size_t)Nout * 64;
  const u16* aTile = A + (size_t)rowBase * 64;
  const u16* bTile = B + (size_t)colBase * 64;

  auto stage = [&](int buf, int kc) {
    const u16* aB = aTile + (size_t)kc * aCS;
    #pragma unroll
    for (int i = 0; i < 4; ++i) {                 // A: 16 calls, 4/wave (16KB tile)
      int c = wave * 4 + i;
      int row = c * 8 + lrow;
      const u16* gp = aB + row * 64 + ((lq ^ (row & 7)) << 3);
      __builtin_amdgcn_global_load_lds((gas_ptr)gp, (las_ptr)(&As[buf][c * 512]), 16, 0, 0);
    }
    const u16* bB = bTile + (size_t)kc * bCS;
    #pragma unroll
    for (int i = 0; i < BCALLS_B / 4; ++i) {      // B: BCALLS_B calls
      int c = wave * (BCALLS_B / 4) + i;
      int row = c * 8 + lrow;
      const u16* gp = bB + row * 64 + ((lq ^ (row & 7)) << 3);
      __builtin_amdgcn_global_load_lds((gas_ptr)gp, (las_ptr)(&Bs[buf][c * 512]), 16, 0, 0);
    }
  };

  stage(0, kcStart);                              // prologue: fill buf0
  int cur = 0;
  for (int t = 0; t < kcLen; ++t) {
    __syncthreads();                              // drains vmcnt -> buf[cur] published
    if (t + 1 < kcLen) stage(cur ^ 1, kcStart + t + 1);   // prefetch BEFORE compute
    const u16* Asb = &As[cur][0];
    const u16* Bsb = &Bs[cur][0];
    #pragma unroll
    for (int kk = 0; kk < 2; ++kk) {              // 32 MFMA per K-step
      const int r0 = 32 * wave + l16;
      const int r1 = r0 + 16;
      short8 a0 = *(const short8*)(Asb + r0 * 64 + ((((kk << 2) + quad) ^ (r0 & 7)) << 3));
      short8 a1 = *(const short8*)(Asb + r1 * 64 + ((((kk << 2) + quad) ^ (r1 & 7)) << 3));
      #pragma unroll
      for (int c = 0; c < CF; ++c) {
        int rb = 16 * c + l16;
        short8 b = *(const short8*)(Bsb + rb * 64 + ((((kk << 2) + quad) ^ (rb & 7)) << 3));
        acc[0][c] = __builtin_amdgcn_mfma_f32_16x16x32_bf16(a0, b, acc[0][c], 0, 0, 0);
        acc[1][c] = __builtin_amdgcn_mfma_f32_16x16x32_bf16(a1, b, acc[1][c], 0, 0, 0);
      }
    }
    cur ^= 1;
  }

  // C/D layout: col = lane&15, row = quad*4 + reg (verified m89/m91)
  #pragma unroll
  for (int rt = 0; rt < 2; ++rt)
    #pragma unroll
    for (int c = 0; c < CF; ++c)
      #pragma unroll
      for (int i = 0; i < 4; ++i) {
        int gr = rowBase + 32 * wave + 16 * rt + quad * 4 + i;
        if (gr < M) {
          int gc = colBase + 16 * c + l16;
          if (OUTM == 1) Cb[(size_t)gr * Nout + gc] = f2bf(acc[rt][c][i]);
          else           atomicAdd(Cf + (size_t)gr * Nout + gc, acc[rt][c][i]);
        }
      }

  // ---- fused el/er epilogue (from f32 acc) ----
  if (OUTM == 1) {
    #pragma unroll
    for (int rt = 0; rt < 2; ++rt)
      #pragma unroll
      for (int i = 0; i < 4; ++i) {
        int gr = rowBase + 32 * wave + 16 * rt + quad * 4 + i;
        #pragma unroll
        for (int hp = 0; hp < 2; ++hp) {
          float sl = 0.f, sr = 0.f;
          #pragma unroll
          for (int cc = 0; cc < 4; ++cc) {
            int c = hp * 4 + cc;
            int gc = colBase + 16 * c + l16;
            float zv = acc[rt][c][i];
            sl += zv * al[gc];
            sr += zv * ar[gc];
          }
          #pragma unroll
          for (int m = 1; m < 16; m <<= 1) {
            sl += __shfl_xor(sl, m, 64);
            sr += __shfl_xor(sr, m, 64);
          }
          if (l16 == 0 && gr < M) {
            int hh = colBase / 64 + hp;
            el[(size_t)gr * 8 + hh] = sl;
            er[(size_t)gr * 8 + hh] = sr;
          }
        }
      }
  } else {
    #pragma unroll
    for (int rt = 0; rt < 2; ++rt)
      #pragma unroll
      for (int i = 0; i < 4; ++i) {
        int gr = rowBase + 32 * wave + 16 * rt + quad * 4 + i;
        float sl = 0.f, sr = 0.f;
        #pragma unroll
        for (int c = 0; c < CF; ++c) {
          int gc = 16 * c + l16;
          float zv = acc[rt][c][i];
          sl += zv * al[gc];
          sr += zv * ar[gc];
        }
        #pragma unroll
        for (int m = 1; m < 16; m <<= 1) {
          sl += __shfl_xor(sl, m, 64);
          sr += __shfl_xor(sr, m, 64);
        }
        if (l16 == 0 && gr < M) {
          atomicAdd(el + gr, sl);
          atomicAdd(er + gr, sr);
        }
      }
  }
}

// ---------- layers 1/2 aggregate: bf16 z gather, 1 wave/node, 8 cols/thread ----------
// out = sum_e exp(v_e) z[src_e] / sum_e exp(v_e)  (shift-invariant softmax, no max pass)
// Epilogue writes next layer's A' K-chunked: [16][Mpad][64] (hi ck 0..7, lo 8..15).
// NOTE (r1/r5 post-mortems): gather is pattern-rate-bound (~3.7 TB/s random 1KB rows);
// neither deeper issue batching (r1) nor column-half working-set tiling (r5) moves it.
// This full-width guarded form is the measured-best (r4: 67.4us).
__global__ __launch_bounds__(64)
void agg_bf16_kernel(const u16* __restrict__ z, const float* __restrict__ el,
                     const float* __restrict__ er, const int* __restrict__ src,
                     const int* __restrict__ rs, u16* __restrict__ a2out, int Mpad)
{
  const int n = blockIdx.x, tid = threadIdx.x;
  const int s = rs[n], e = rs[n + 1];
  const int c0 = tid * 8;                          // 8 bf16 cols = 16 B/lane
  const int h = tid >> 3;                          // c0 / 64
  const float er_h = er[(size_t)n * 8 + h];

  float acc[8];
  #pragma unroll
  for (int j = 0; j < 8; ++j) acc[j] = 0.f;
  float den = 0.f;

  for (int k0 = s; k0 < e; k0 += 8) {
    const int kc = e - k0;
    #pragma unroll
    for (int kk = 0; kk < 8; ++kk) {
      if (kk < kc) {                               // wave-uniform guard
        int si = src[k0 + kk];                     // broadcast load
        float v = el[(size_t)si * 8 + h] + er_h;   // broadcast load
        v = (v > 0.f) ? v : 0.2f * v;              // leaky_relu 0.2
        float wgt = __expf(v);
        u32x4 zz = *(const u32x4*)(z + (size_t)si * 512 + c0);  // 16B/lane coalesced
        #pragma unroll
        for (int j = 0; j < 4; ++j) {
          acc[2 * j]     += wgt * bf_lo(zz[j]);
          acc[2 * j + 1] += wgt * bf_hi(zz[j]);
        }
        den += wgt;
      }
    }
  }

  const float r = (e > s) ? (1.f / den) : 0.f;     // deg==0 -> zeros (elu(0)=0)
  u32x4 hp, lp;
  #pragma unroll
  for (int j = 0; j < 4; ++j) {
    float o0 = acc[2 * j] * r, o1 = acc[2 * j + 1] * r;
    o0 = (o0 > 0.f) ? o0 : (__expf(o0) - 1.f);     // elu
    o1 = (o1 > 0.f) ? o1 : (__expf(o1) - 1.f);
    u16 h0 = f2bf(o0), h1 = f2bf(o1);
    u16 l0 = f2bf(o0 - bf2f(h0)), l1 = f2bf(o1 - bf2f(h1));
    hp[j] = ((u32)h1 << 16) | h0;
    lp[j] = ((u32)l1 << 16) | l0;
  }
  // tiled A' store: chunk = c0/64, offset = c0%64 (8 lanes -> 128B contiguous runs)
  const int ck = tid >> 3;
  const int ko = (tid & 7) << 3;
  const size_t cs = (size_t)Mpad * 64;
  u16* p = a2out + (size_t)n * 64 + ko;
  *(u32x4*)(p + (size_t)ck * cs) = hp;
  *(u32x4*)(p + (size_t)(ck + 8) * cs) = lp;
}

// ---------- layer 3 aggregate: f32 z3 (3.2 MB, L2-resident), 32 cols ----------
__global__ __launch_bounds__(64)
void agg3_kernel(const float* __restrict__ z, const float* __restrict__ el,
                 const float* __restrict__ er, const int* __restrict__ src,
                 const int* __restrict__ rs, float* __restrict__ out)
{
  const int n = blockIdx.x, tid = threadIdx.x;
  const int s = rs[n], e = rs[n + 1];
  const bool active = (tid < 32);
  const float er_n = er[n];
  float acc = 0.f, den = 0.f;

  for (int k0 = s; k0 < e; k0 += 8) {
    const int kc = e - k0;
    #pragma unroll
    for (int kk = 0; kk < 8; ++kk) {
      if (kk < kc) {
        int si = src[k0 + kk];
        float v = el[si] + er_n;
        v = (v > 0.f) ? v : 0.2f * v;
        float wgt = __expf(v);
        if (active) acc += wgt * z[(size_t)si * 32 + tid];
        den += wgt;
      }
    }
  }
  if (active) out[(size_t)n * 32 + tid] = (e > s) ? (acc / den) : 0.f;
}

extern "C" void kernel_launch(void* const* d_in, const int* in_sizes, int n_in,
                              void* d_out, int out_size, void* d_ws, size_t ws_size,
                              hipStream_t stream)
{
  constexpr int N = 25000, E = 400000, K1 = 256, HF = 512, CLS = 32;
  constexpr int Mpad = 25088;                       // 196 * 128
  const float* h   = (const float*)d_in[0];
  const int*   src = (const int*)d_in[1];
  const int*   dst = (const int*)d_in[2];
  const float* W1  = (const float*)d_in[3];
  const float* al1 = (const float*)d_in[4];
  const float* ar1 = (const float*)d_in[5];
  const float* W2  = (const float*)d_in[6];
  const float* al2 = (const float*)d_in[7];
  const float* ar2 = (const float*)d_in[8];
  const float* W3  = (const float*)d_in[9];
  const float* al3 = (const float*)d_in[10];
  const float* ar3 = (const float*)d_in[11];
  float* out = (float*)d_out;

  char* w = (char*)d_ws;
  auto take = [&](size_t bytes) {
    char* p = w;
    w += (bytes + 255) & ~(size_t)255;
    return p;
  };
  int*   rs = (int*)  take((size_t)(N + 1) * sizeof(int));
  float* el = (float*)take((size_t)N * 8 * sizeof(float));
  float* er = (float*)take((size_t)N * 8 * sizeof(float));
  float* z3 = (float*)take((size_t)N * CLS * sizeof(float));          // 3.2 MB
  u16*   zb = (u16*)  take((size_t)N * HF * sizeof(u16));             // 25.6 MB
  u16*   A2 = (u16*)  take((size_t)16 * Mpad * 64 * sizeof(u16));     // 51.4 MB
  u16*   B1 = (u16*)  take((size_t)8  * HF * 64 * sizeof(u16));       // 0.52 MB
  u16*   B2 = (u16*)  take((size_t)16 * HF * 64 * sizeof(u16));       // 1.05 MB
  u16*   B3 = (u16*)  take((size_t)16 * CLS * 64 * sizeof(u16));      // 64 KB
  u16*   A1 = A2;       // layer-1 A (8 chunks) aliases A2; dead before agg1 writes

  // ---- independent prep ----
  rowstart_kernel<<<dim3((N + 1 + 255) / 256), 256, 0, stream>>>(dst, rs, N, E);
  splitA_kernel<<<dim3((N * K1) / 256), 256, 0, stream>>>(h, A1, N, Mpad);
  splitW_kernel<<<dim3(1600), 256, 0, stream>>>(W1, W2, W3, B1, B2, B3);

  const int gemmBlocks = 4 * (Mpad / 128);          // 784, 1-D XCD-grouped decode

  // ---- Layer 1: K'=512 (8 chunks), elr fused ----
  gemm_bt_kernel<128, 1><<<dim3(gemmBlocks), 256, 0, stream>>>(A1, B1, nullptr, zb,
      al1, ar1, el, er, N, HF, Mpad, 8);
  agg_bf16_kernel<<<dim3(N), 64, 0, stream>>>(zb, el, er, src, rs, A2, Mpad);

  // ---- Layer 2: K'=1024 (16 chunks), elr fused ----
  gemm_bt_kernel<128, 1><<<dim3(gemmBlocks), 256, 0, stream>>>(A2, B2, nullptr, zb,
      al2, ar2, el, er, N, HF, Mpad, 16);
  agg_bf16_kernel<<<dim3(N), 64, 0, stream>>>(zb, el, er, src, rs, A2, Mpad);

  // ---- Layer 3: split-K=4 (4 chunks each) + atomicAdd, elr fused (atomic) ----
  zero3_kernel<<<dim3((N * CLS + 2 * N + 255) / 256), 256, 0, stream>>>(z3, el, er, N * CLS, N);
  gemm_bt_kernel<32, 2><<<dim3(4, Mpad / 128), 256, 0, stream>>>(A2, B3, z3, nullptr,
      al3, ar3, el, er, N, CLS, Mpad, 4);
  agg3_kernel<<<dim3(N), 64, 0, stream>>>(z3, el, er, src, rs, out);
}

// Round 7
// 370.292 us; speedup vs baseline: 1.0793x; 1.0123x over previous
//
#include <hip/hip_runtime.h>
#include <cstdint>

#define DEVINL __device__ __forceinline__

typedef uint16_t u16;
typedef uint32_t u32;
typedef uint64_t u64;
typedef __attribute__((ext_vector_type(8))) short short8;
typedef __attribute__((ext_vector_type(4))) float floatx4;
typedef __attribute__((ext_vector_type(4))) u32 u32x4;
typedef const __attribute__((address_space(1))) void* gas_ptr;
typedef __attribute__((address_space(3))) void* las_ptr;

DEVINL u16 f2bf(float f) {
  u32 u = __float_as_uint(f);
  u32 r = u + 0x7FFFu + ((u >> 16) & 1u);   // RNE
  return (u16)(r >> 16);
}
DEVINL float bf2f(u16 b) { return __uint_as_float((u32)b << 16); }
DEVINL float bf_lo(u32 u) { return __uint_as_float(u << 16); }
DEVINL float bf_hi(u32 u) { return __uint_as_float(u & 0xFFFF0000u); }

// Operand layout for GEMM: K-chunked tiles  T[ck][row][64], ck = k/64.
// A' rows padded to Mpad=25088 so block row-tiles read contiguous 16KB with no clamp.

// ---------- fused prep: splitA + splitW + rowstart + zero(z3), one dispatch ----------
// Block ranges: [0,25000) splitA, [25000,26600) splitW, [26600,26698) rowstart,
// [26698,29823) zero z3. All independent elementwise work.
__global__ __launch_bounds__(256)
void prep_kernel(const int* __restrict__ dst, int* __restrict__ rs,
                 const float* __restrict__ h, u16* __restrict__ A1,
                 const float* __restrict__ W1, const float* __restrict__ W2,
                 const float* __restrict__ W3, u16* __restrict__ B1,
                 u16* __restrict__ B2, u16* __restrict__ B3,
                 float* __restrict__ z3, int N, int E, int Mpad)
{
  const int b = blockIdx.x, tid = threadIdx.x;
  if (b < 25000) {                                // splitA: h[N][256] -> [8][Mpad][64]
    int idx = b * 256 + tid;                      // exact: 25000*256 = N*256
    int m = idx >> 8, k = idx & 255;
    float a = h[idx];
    u16 hi = f2bf(a);
    u16 lo = f2bf(a - bf2f(hi));
    size_t cs = (size_t)Mpad * 64;
    size_t pos = (size_t)m * 64 + (k & 63);
    A1[(size_t)(k >> 6) * cs + pos] = hi;         // hi chunks 0..3
    A1[(size_t)((k >> 6) + 4) * cs + pos] = lo;   // lo chunks 4..7
    return;
  }
  if (b < 26600) {                                // splitW (bf16 hi duplicated)
    int idx = (b - 25000) * 256 + tid;
    if (idx < 512 * 256) {                        // W1 [512][256] -> [8][512][64]
      int m = idx >> 8, k = idx & 255;
      u16 hh = f2bf(W1[idx]);
      size_t cs = 512 * 64;
      size_t pos = (size_t)m * 64 + (k & 63);
      B1[(size_t)(k >> 6) * cs + pos] = hh;
      B1[(size_t)((k >> 6) + 4) * cs + pos] = hh;
      return;
    }
    idx -= 512 * 256;
    if (idx < 512 * 512) {                        // W2 [512][512] -> [16][512][64]
      int m = idx >> 9, k = idx & 511;
      u16 hh = f2bf(W2[idx]);
      size_t cs = 512 * 64;
      size_t pos = (size_t)m * 64 + (k & 63);
      B2[(size_t)(k >> 6) * cs + pos] = hh;
      B2[(size_t)((k >> 6) + 8) * cs + pos] = hh;
      return;
    }
    idx -= 512 * 512;
    {                                             // W3 [32][512] -> [16][32][64]
      int m = idx >> 9, k = idx & 511;
      u16 hh = f2bf(W3[idx]);
      size_t cs = 32 * 64;
      size_t pos = (size_t)m * 64 + (k & 63);
      B3[(size_t)(k >> 6) * cs + pos] = hh;
      B3[(size_t)((k >> 6) + 8) * cs + pos] = hh;
      return;
    }
  }
  if (b < 26698) {                                // rowstart: lower_bound over sorted dst
    int n = (b - 26600) * 256 + tid;
    if (n > N) return;
    int lo = 0, hi = E;
    while (lo < hi) { int mid = (lo + hi) >> 1; if (dst[mid] < n) lo = mid + 1; else hi = mid; }
    rs[n] = lo;
    return;
  }
  {                                               // zero z3 (layer-3 atomic target)
    int i = (b - 26698) * 256 + tid;
    if (i < N * 32) z3[i] = 0.f;
  }
}

// ---------- GEMM: C[M,Nout] = A'[M,K'] * B'[Nout,K']^T, K-chunked operands ----------
// R7: 8 waves (512 thr), wave owns 16 rows -> 16 waves/CU at the same 64KB LDS
// (2 blocks/CU), doubling latency-hiding TLP vs the 4-wave version (occupancy 17-20%).
// 2-phase double-buffer (R6): STAGE(t+1) issued BEFORE compute(t), one barrier/step.
// Staging: one global_load_lds call = 64 lanes x 16B = 512 u16 = 8 tile-rows.
//   A tile 128x64 = 16 calls (2/wave); B tile BNx64 = BN/8 calls.
// LDS XOR-swizzle (granule ^= row&7): pre-swizzled GLOBAL source + swizzled ds_read.
// OUTM 1: bf16 C store + el/er store epilogue; XCD-grouped bid decode.
// OUTM 2: split-K z3 atomicAdd + NON-atomic el/er partials elp/erp[4][M]
//         (each (chunk,row) owned by exactly one block; agg3 sums the 4).
template<int BN, int OUTM>
__global__ __launch_bounds__(512)
void gemm_bt_kernel(const u16* __restrict__ A, const u16* __restrict__ B,
                    float* __restrict__ Cf, u16* __restrict__ Cb,
                    const float* __restrict__ al, const float* __restrict__ ar,
                    float* __restrict__ el, float* __restrict__ er,
                    int M, int Nout, int Mpad, int kcLen)
{
  constexpr int BM = 128, CF = BN / 16;
  constexpr int BCALLS_B = (BN * 64) / 512;       // 16 for BN=128, 4 for BN=32
  __shared__ __align__(16) u16 As[2][BM * 64];    // 2 x 16 KB
  __shared__ __align__(16) u16 Bs[2][BN * 64];
  const int tid  = threadIdx.x;
  const int wave = tid >> 6;                      // 0..7
  const int lane = tid & 63;
  const int quad = lane >> 4;
  const int l16  = lane & 15;
  const int lrow = lane >> 3;                     // sub-row within a 512-elem call
  const int lq   = lane & 7;                      // 16B-granule within row

  int bx, by;
  if (OUTM == 1) {
    // XCD grouping: bid = y%8 + 8*x + 32*(y/8) for full groups of 8 y's.
    int bid = blockIdx.x;
    int nY = (M + 127) >> 7;
    int fullG = nY >> 3;
    if ((bid >> 5) < fullG) {
      int rem = bid & 31;
      by = ((bid >> 5) << 3) + (rem & 7);
      bx = rem >> 3;
    } else {
      int t = bid - (fullG << 5);
      int tailY = nY - (fullG << 3);
      by = (fullG << 3) + t % tailY;
      bx = t / tailY;
    }
  } else { bx = blockIdx.x; by = blockIdx.y; }

  const int rowBase = by * BM;
  const int colBase = (OUTM == 2) ? 0 : bx * BN;
  const int kcStart = (OUTM == 2) ? bx * kcLen : 0;

  floatx4 acc[CF];
  #pragma unroll
  for (int c = 0; c < CF; ++c)
    acc[c] = (floatx4){0.f, 0.f, 0.f, 0.f};

  const size_t aCS = (size_t)Mpad * 64;
  const size_t bCS = (size_t)Nout * 64;
  const u16* aTile = A + (size_t)rowBase * 64;
  const u16* bTile = B + (size_t)colBase * 64;

  auto stage = [&](int buf, int kc) {
    const u16* aB = aTile + (size_t)kc * aCS;
    #pragma unroll
    for (int i = 0; i < 2; ++i) {                 // A: 16 calls, 2/wave (16KB tile)
      int c = wave + 8 * i;
      int row = c * 8 + lrow;
      const u16* gp = aB + row * 64 + ((lq ^ (row & 7)) << 3);
      __builtin_amdgcn_global_load_lds((gas_ptr)gp, (las_ptr)(&As[buf][c * 512]), 16, 0, 0);
    }
    const u16* bB = bTile + (size_t)kc * bCS;
    #pragma unroll
    for (int i = 0; i < (BCALLS_B + 7) / 8; ++i) {
      int c = wave + 8 * i;
      if (c < BCALLS_B) {
        int row = c * 8 + lrow;
        const u16* gp = bB + row * 64 + ((lq ^ (row & 7)) << 3);
        __builtin_amdgcn_global_load_lds((gas_ptr)gp, (las_ptr)(&Bs[buf][c * 512]), 16, 0, 0);
      }
    }
  };

  stage(0, kcStart);                              // prologue: fill buf0
  int cur = 0;
  for (int t = 0; t < kcLen; ++t) {
    __syncthreads();                              // drains vmcnt -> buf[cur] published
    if (t + 1 < kcLen) stage(cur ^ 1, kcStart + t + 1);   // prefetch BEFORE compute
    const u16* Asb = &As[cur][0];
    const u16* Bsb = &Bs[cur][0];
    const int r0 = 16 * wave + l16;               // this wave's 16 rows
    #pragma unroll
    for (int kk = 0; kk < 2; ++kk) {
      short8 a0 = *(const short8*)(Asb + r0 * 64 + ((((kk << 2) + quad) ^ (r0 & 7)) << 3));
      #pragma unroll
      for (int c = 0; c < CF; ++c) {
        int rb = 16 * c + l16;
        short8 b = *(const short8*)(Bsb + rb * 64 + ((((kk << 2) + quad) ^ (rb & 7)) << 3));
        acc[c] = __builtin_amdgcn_mfma_f32_16x16x32_bf16(a0, b, acc[c], 0, 0, 0);
      }
    }
    cur ^= 1;
  }

  // C/D layout: col = lane&15, row = quad*4 + reg (verified m89/m91)
  #pragma unroll
  for (int c = 0; c < CF; ++c)
    #pragma unroll
    for (int i = 0; i < 4; ++i) {
      int gr = rowBase + 16 * wave + quad * 4 + i;
      if (gr < M) {
        int gc = colBase + 16 * c + l16;
        if (OUTM == 1) Cb[(size_t)gr * Nout + gc] = f2bf(acc[c][i]);
        else           atomicAdd(Cf + (size_t)gr * Nout + gc, acc[c][i]);
      }
    }

  // ---- fused el/er epilogue (from f32 acc) ----
  if (OUTM == 1) {
    #pragma unroll
    for (int i = 0; i < 4; ++i) {
      int gr = rowBase + 16 * wave + quad * 4 + i;
      #pragma unroll
      for (int hp = 0; hp < 2; ++hp) {
        float sl = 0.f, sr = 0.f;
        #pragma unroll
        for (int cc = 0; cc < 4; ++cc) {
          int c = hp * 4 + cc;
          int gc = colBase + 16 * c + l16;
          float zv = acc[c][i];
          sl += zv * al[gc];
          sr += zv * ar[gc];
        }
        #pragma unroll
        for (int m = 1; m < 16; m <<= 1) {        // reduce over l16 within each quad
          sl += __shfl_xor(sl, m, 64);
          sr += __shfl_xor(sr, m, 64);
        }
        if (l16 == 0 && gr < M) {
          int hh = colBase / 64 + hp;
          el[(size_t)gr * 8 + hh] = sl;
          er[(size_t)gr * 8 + hh] = sr;
        }
      }
    }
  } else {
    // el/er split-K partials: elp[bx*M + gr], erp[bx*M + gr] (non-atomic).
    #pragma unroll
    for (int i = 0; i < 4; ++i) {
      int gr = rowBase + 16 * wave + quad * 4 + i;
      float sl = 0.f, sr = 0.f;
      #pragma unroll
      for (int c = 0; c < CF; ++c) {
        int gc = 16 * c + l16;
        float zv = acc[c][i];
        sl += zv * al[gc];
        sr += zv * ar[gc];
      }
      #pragma unroll
      for (int m = 1; m < 16; m <<= 1) {
        sl += __shfl_xor(sl, m, 64);
        sr += __shfl_xor(sr, m, 64);
      }
      if (l16 == 0 && gr < M) {
        el[(size_t)bx * M + gr] = sl;
        er[(size_t)bx * M + gr] = sr;
      }
    }
  }
}

// ---------- layers 1/2 aggregate: bf16 z gather, 1 wave/node, 8 cols/thread ----------
// out = sum_e exp(v_e) z[src_e] / sum_e exp(v_e)  (shift-invariant softmax, no max pass)
// Epilogue writes next layer's A' K-chunked: [16][Mpad][64] (hi ck 0..7, lo 8..15).
// NOTE (r1/r5 post-mortems): gather is pattern-rate-bound (~3.7 TB/s random 1KB rows);
// neither deeper issue batching (r1) nor column-half working-set tiling (r5) moves it.
// This full-width guarded form is the measured-best (r4/r6: ~67.5-68.4us).
__global__ __launch_bounds__(64)
void agg_bf16_kernel(const u16* __restrict__ z, const float* __restrict__ el,
                     const float* __restrict__ er, const int* __restrict__ src,
                     const int* __restrict__ rs, u16* __restrict__ a2out, int Mpad)
{
  const int n = blockIdx.x, tid = threadIdx.x;
  const int s = rs[n], e = rs[n + 1];
  const int c0 = tid * 8;                          // 8 bf16 cols = 16 B/lane
  const int h = tid >> 3;                          // c0 / 64
  const float er_h = er[(size_t)n * 8 + h];

  float acc[8];
  #pragma unroll
  for (int j = 0; j < 8; ++j) acc[j] = 0.f;
  float den = 0.f;

  for (int k0 = s; k0 < e; k0 += 8) {
    const int kc = e - k0;
    #pragma unroll
    for (int kk = 0; kk < 8; ++kk) {
      if (kk < kc) {                               // wave-uniform guard
        int si = src[k0 + kk];                     // broadcast load
        float v = el[(size_t)si * 8 + h] + er_h;   // broadcast load
        v = (v > 0.f) ? v : 0.2f * v;              // leaky_relu 0.2
        float wgt = __expf(v);
        u32x4 zz = *(const u32x4*)(z + (size_t)si * 512 + c0);  // 16B/lane coalesced
        #pragma unroll
        for (int j = 0; j < 4; ++j) {
          acc[2 * j]     += wgt * bf_lo(zz[j]);
          acc[2 * j + 1] += wgt * bf_hi(zz[j]);
        }
        den += wgt;
      }
    }
  }

  const float r = (e > s) ? (1.f / den) : 0.f;     // deg==0 -> zeros (elu(0)=0)
  u32x4 hp, lp;
  #pragma unroll
  for (int j = 0; j < 4; ++j) {
    float o0 = acc[2 * j] * r, o1 = acc[2 * j + 1] * r;
    o0 = (o0 > 0.f) ? o0 : (__expf(o0) - 1.f);     // elu
    o1 = (o1 > 0.f) ? o1 : (__expf(o1) - 1.f);
    u16 h0 = f2bf(o0), h1 = f2bf(o1);
    u16 l0 = f2bf(o0 - bf2f(h0)), l1 = f2bf(o1 - bf2f(h1));
    hp[j] = ((u32)h1 << 16) | h0;
    lp[j] = ((u32)l1 << 16) | l0;
  }
  // tiled A' store: chunk = c0/64, offset = c0%64 (8 lanes -> 128B contiguous runs)
  const int ck = tid >> 3;
  const int ko = (tid & 7) << 3;
  const size_t cs = (size_t)Mpad * 64;
  u16* p = a2out + (size_t)n * 64 + ko;
  *(u32x4*)(p + (size_t)ck * cs) = hp;
  *(u32x4*)(p + (size_t)(ck + 8) * cs) = lp;
}

// ---------- layer 3 aggregate: f32 z3 (3.2 MB, L2-resident), 32 cols ----------
// el/er come as split-K partials elp/erp[4][N]; sum the 4 (fixed order).
__global__ __launch_bounds__(64)
void agg3_kernel(const float* __restrict__ z, const float* __restrict__ elp,
                 const float* __restrict__ erp, const int* __restrict__ src,
                 const int* __restrict__ rs, float* __restrict__ out, int N)
{
  const int n = blockIdx.x, tid = threadIdx.x;
  const int s = rs[n], e = rs[n + 1];
  const bool active = (tid < 32);
  const float er_n = erp[n] + erp[N + n] + erp[2 * N + n] + erp[3 * N + n];
  float acc = 0.f, den = 0.f;

  for (int k0 = s; k0 < e; k0 += 8) {
    const int kc = e - k0;
    #pragma unroll
    for (int kk = 0; kk < 8; ++kk) {
      if (kk < kc) {
        int si = src[k0 + kk];
        float elv = elp[si] + elp[N + si] + elp[2 * N + si] + elp[3 * N + si];
        float v = elv + er_n;
        v = (v > 0.f) ? v : 0.2f * v;
        float wgt = __expf(v);
        if (active) acc += wgt * z[(size_t)si * 32 + tid];
        den += wgt;
      }
    }
  }
  if (active) out[(size_t)n * 32 + tid] = (e > s) ? (acc / den) : 0.f;
}

extern "C" void kernel_launch(void* const* d_in, const int* in_sizes, int n_in,
                              void* d_out, int out_size, void* d_ws, size_t ws_size,
                              hipStream_t stream)
{
  constexpr int N = 25000, E = 400000, K1 = 256, HF = 512, CLS = 32;
  constexpr int Mpad = 25088;                       // 196 * 128
  const float* h   = (const float*)d_in[0];
  const int*   src = (const int*)d_in[1];
  const int*   dst = (const int*)d_in[2];
  const float* W1  = (const float*)d_in[3];
  const float* al1 = (const float*)d_in[4];
  const float* ar1 = (const float*)d_in[5];
  const float* W2  = (const float*)d_in[6];
  const float* al2 = (const float*)d_in[7];
  const float* ar2 = (const float*)d_in[8];
  const float* W3  = (const float*)d_in[9];
  const float* al3 = (const float*)d_in[10];
  const float* ar3 = (const float*)d_in[11];
  float* out = (float*)d_out;

  char* w = (char*)d_ws;
  auto take = [&](size_t bytes) {
    char* p = w;
    w += (bytes + 255) & ~(size_t)255;
    return p;
  };
  int*   rs  = (int*)  take((size_t)(N + 1) * sizeof(int));
  float* el  = (float*)take((size_t)N * 8 * sizeof(float));
  float* er  = (float*)take((size_t)N * 8 * sizeof(float));
  float* elp = (float*)take((size_t)4 * N * sizeof(float));           // 400 KB
  float* erp = (float*)take((size_t)4 * N * sizeof(float));           // 400 KB
  float* z3  = (float*)take((size_t)N * CLS * sizeof(float));         // 3.2 MB
  u16*   zb  = (u16*)  take((size_t)N * HF * sizeof(u16));            // 25.6 MB
  u16*   A2  = (u16*)  take((size_t)16 * Mpad * 64 * sizeof(u16));    // 51.4 MB
  u16*   B1  = (u16*)  take((size_t)8  * HF * 64 * sizeof(u16));      // 0.52 MB
  u16*   B2  = (u16*)  take((size_t)16 * HF * 64 * sizeof(u16));      // 1.05 MB
  u16*   B3  = (u16*)  take((size_t)16 * CLS * 64 * sizeof(u16));     // 64 KB
  u16*   A1  = A2;      // layer-1 A (8 chunks) aliases A2; dead before agg1 writes

  // ---- fused prep: splitA | splitW | rowstart | zero(z3) ----
  prep_kernel<<<dim3(25000 + 1600 + 98 + 3125), 256, 0, stream>>>(
      dst, rs, h, A1, W1, W2, W3, B1, B2, B3, z3, N, E, Mpad);

  const int gemmBlocks = 4 * (Mpad / 128);          // 784, 1-D XCD-grouped decode

  // ---- Layer 1: K'=512 (8 chunks), elr fused ----
  gemm_bt_kernel<128, 1><<<dim3(gemmBlocks), 512, 0, stream>>>(A1, B1, nullptr, zb,
      al1, ar1, el, er, N, HF, Mpad, 8);
  agg_bf16_kernel<<<dim3(N), 64, 0, stream>>>(zb, el, er, src, rs, A2, Mpad);

  // ---- Layer 2: K'=1024 (16 chunks), elr fused ----
  gemm_bt_kernel<128, 1><<<dim3(gemmBlocks), 512, 0, stream>>>(A2, B2, nullptr, zb,
      al2, ar2, el, er, N, HF, Mpad, 16);
  agg_bf16_kernel<<<dim3(N), 64, 0, stream>>>(zb, el, er, src, rs, A2, Mpad);

  // ---- Layer 3: split-K=4 + z3 atomicAdd, el/er non-atomic partials ----
  gemm_bt_kernel<32, 2><<<dim3(4, Mpad / 128), 512, 0, stream>>>(A2, B3, z3, nullptr,
      al3, ar3, elp, erp, N, CLS, Mpad, 4);
  agg3_kernel<<<dim3(N), 64, 0, stream>>>(z3, elp, erp, src, rs, out, N);
}